// Round 4
// baseline (216.640 us; speedup 1.0000x reference)
//
#include <hip/hip_runtime.h>
#include <hip/hip_cooperative_groups.h>
#include <math.h>

namespace cg = cooperative_groups;

#define H_IMG 256
#define W_IMG 512
#define FS    14
#define L     196
#define DM    384
#define HID   96
#define TPB   16     // tokens per unit in phase B

// One cooperative kernel:
//   phase A : 16x16 avg-pool of wraparound crop -> pooled[] in workspace
//             (grid-stride over B*14 units, 224 active lanes each, 28 waves/CU)
//   phase A': last block folds A = Wp@w1 (3x96), B0 = bp@w1+b1 (runs concurrently)
//   grid.sync()
//   phase B : per-token fusion weight (16 lanes/token) + bilinear combos
//   phase C : stream out = gf + fw*(wsum*bp + ps0..2 . Wp) as float4
__global__ __launch_bounds__(256, 8) void mega_kernel(
    const float* __restrict__ img, const float* __restrict__ pos,
    const float* __restrict__ gf,  const float* __restrict__ Wp,
    const float* __restrict__ bp,  const float* __restrict__ w1,
    const float* __restrict__ b1,  const float* __restrict__ w2,
    const float* __restrict__ b2,  float* __restrict__ out,
    float* __restrict__ pooled, float* __restrict__ Af, float* __restrict__ B0f,
    int B)
{
    const int HW   = H_IMG * W_IMG;
    const int tid  = threadIdx.x;
    const int nPool = B * FS;
    const int nTok  = B * L;
    const int nUB   = (nTok + TPB - 1) / TPB;

    __shared__ float4 sWp4[3 * DM / 4];   // 288
    __shared__ float4 sbp4[DM / 4];       // 96
    __shared__ float  sA[3 * HID];
    __shared__ float  sB0[HID];
    __shared__ float  sw2[HID];
    __shared__ float  sMeta[TPB][5];

    // stage small read-only weights (overlaps phase A)
    for (int k = tid; k < 288; k += 256) sWp4[k] = ((const float4*)Wp)[k];
    for (int k = tid; k < 96;  k += 256) sbp4[k] = ((const float4*)bp)[k];
    for (int k = tid; k < HID; k += 256) sw2[k]  = w2[k];

    // ---- phase A: pooling ----
    for (int u = blockIdx.x; u < nPool; u += gridDim.x) {
        int b = u / FS, i = u - b * FS;
        float px = fminf(fmaxf(pos[2 * b + 0], 0.f), 1.f);
        float py = fminf(fmaxf(pos[2 * b + 1], 0.f), 1.f);
        int xs = ((int)truncf(px * 512.f - 112.f)) % 512; if (xs < 0) xs += 512;
        int ys = (int)floorf(fminf(fmaxf(py * 256.f - 112.f, 0.f), 32.f));
        if (tid < 224) {
            int col = xs + tid; if (col >= W_IMG) col -= W_IMG;   // wraparound
            int row0 = ys + i * 16;
            const float* ip = img + (size_t)b * 3 * HW + (size_t)row0 * W_IMG + col;
            float a0 = 0.f, a1 = 0.f, a2 = 0.f;
            #pragma unroll
            for (int dy = 0; dy < 16; ++dy) {
                const float* r = ip + dy * W_IMG;
                a0 += r[0];
                a1 += r[HW];
                a2 += r[2 * HW];
            }
            #pragma unroll
            for (int d = 1; d < 16; d <<= 1) {
                a0 += __shfl_xor(a0, d);
                a1 += __shfl_xor(a1, d);
                a2 += __shfl_xor(a2, d);
            }
            if ((tid & 15) == 0) {
                int li = i * FS + (tid >> 4);
                pooled[((size_t)b * 3 + 0) * L + li] = a0 * (1.f / 256.f);
                pooled[((size_t)b * 3 + 1) * L + li] = a1 * (1.f / 256.f);
                pooled[((size_t)b * 3 + 2) * L + li] = a2 * (1.f / 256.f);
            }
        }
    }

    // ---- phase A': weight fold on the last (pool-idle) block ----
    if (blockIdx.x == gridDim.x - 1 && tid < HID) {
        float a0 = 0.f, a1 = 0.f, a2 = 0.f, ab = 0.f;
        #pragma unroll 4
        for (int d = 0; d < DM; ++d) {
            float wv = w1[d * HID + tid];
            a0 += Wp[d] * wv;
            a1 += Wp[DM + d] * wv;
            a2 += Wp[2 * DM + d] * wv;
            ab += bp[d] * wv;
        }
        Af[tid] = a0; Af[HID + tid] = a1; Af[2 * HID + tid] = a2;
        B0f[tid] = ab + b1[tid];
    }

    __threadfence();
    cg::this_grid().sync();

    // pull folded MLP matrices into LDS
    if (tid < 3 * HID) sA[tid] = Af[tid];
    if (tid < HID)     sB0[tid] = B0f[tid];
    __syncthreads();

    float b2v = b2[0];

    // ---- phase B + C: grid-stride over token units ----
    for (int u = blockIdx.x; u < nUB; u += gridDim.x) {
        int g = tid >> 4, s = tid & 15;           // token in unit, lane in token
        int token = u * TPB + g; if (token >= nTok) token = nTok - 1;
        int b = token / L, l = token - b * L;
        const float* pb = pooled + (size_t)b * 3 * L;
        float p0 = pb[l], p1 = pb[L + l], p2 = pb[2 * L + l];

        float acc = 0.f;
        #pragma unroll
        for (int m = 0; m < 6; ++m) {
            int k = s + 16 * m;
            float x = sB0[k] + p0 * sA[k] + p1 * sA[HID + k] + p2 * sA[2 * HID + k];
            float e = __expf(1.5957691216057308f * (x + 0.044715f * x * x * x));
            float th = 1.f - 2.f / (e + 1.f);     // tanh, saturates cleanly
            acc += 0.5f * x * (1.f + th) * sw2[k];
        }
        acc += __shfl_xor(acc, 1);
        acc += __shfl_xor(acc, 2);
        acc += __shfl_xor(acc, 4);
        acc += __shfl_xor(acc, 8);

        if (s == 0) {
            float fw = 1.f / (1.f + __expf(-(acc + b2v)));

            float px = fminf(fmaxf(pos[2 * b + 0], 0.f), 1.f);
            float py = fminf(fmaxf(pos[2 * b + 1], 0.f), 1.f);
            int xs = ((int)truncf(px * 512.f - 112.f)) % 512; if (xs < 0) xs += 512;
            int ys = (int)floorf(fminf(fmaxf(py * 256.f - 112.f, 0.f), 32.f));

            int i = l / FS, j = l - i * FS;
            float uj = ((j + 0.5f) * 2.f) / 14.f - 1.f;
            float ui = ((i + 0.5f) * 2.f) / 14.f - 1.f;
            float gx = (224.f / 512.f) * uj + ((2.f * (float)xs + 224.f) / 512.f - 1.f);
            float gy = (224.f / 256.f) * ui + ((2.f * (float)ys + 224.f) / 256.f - 1.f);
            float ix = (gx + 1.f) * 7.f - 0.5f;
            float iy = (gy + 1.f) * 7.f - 0.5f;
            float x0f = floorf(ix), y0f = floorf(iy);
            float wx1 = ix - x0f, wx0 = 1.f - wx1;
            float wy1 = iy - y0f, wy0 = 1.f - wy1;
            int x0 = (int)x0f, y0 = (int)y0f, x1 = x0 + 1, y1 = y0 + 1;

            float ps0 = 0.f, ps1 = 0.f, ps2 = 0.f, wsum = 0.f;
            const int   cx[4] = { x0, x1, x0, x1 };
            const int   cy[4] = { y0, y0, y1, y1 };
            const float cw[4] = { wy0 * wx0, wy0 * wx1, wy1 * wx0, wy1 * wx1 };
            #pragma unroll
            for (int n = 0; n < 4; ++n) {
                int X = cx[n], Y = cy[n];
                if (X >= 0 && X < FS && Y >= 0 && Y < FS) {
                    float w = cw[n];
                    int li = Y * FS + X;
                    ps0 += w * pb[li];
                    ps1 += w * pb[L + li];
                    ps2 += w * pb[2 * L + li];
                    wsum += w;
                }
            }
            sMeta[g][0] = fw;  sMeta[g][1] = wsum;
            sMeta[g][2] = ps0; sMeta[g][3] = ps1; sMeta[g][4] = ps2;
        }
        __syncthreads();

        // phase C: 16 tokens * 96 float4 = 1536 items, 6 iterations of 256
        size_t base4 = (size_t)u * TPB * (DM / 4);
        const float4* gf4  = (const float4*)gf  + base4;
        float4*       out4 = (float4*)out       + base4;
        long long maxItem = (long long)(nTok - u * TPB) * (DM / 4);
        #pragma unroll
        for (int it = 0; it < 6; ++it) {
            int item = it * 256 + tid;
            if (item >= maxItem) break;
            int tl = item / (DM / 4);
            int d4 = item - tl * (DM / 4);
            float fw   = sMeta[tl][0];
            float wsum = sMeta[tl][1];
            float ps0  = sMeta[tl][2];
            float ps1  = sMeta[tl][3];
            float ps2  = sMeta[tl][4];
            float4 g4 = gf4[item];
            float4 W0 = sWp4[d4];
            float4 W1 = sWp4[96 + d4];
            float4 W2 = sWp4[192 + d4];
            float4 BV = sbp4[d4];
            float4 o;
            o.x = g4.x + fw * (wsum * BV.x + ps0 * W0.x + ps1 * W1.x + ps2 * W2.x);
            o.y = g4.y + fw * (wsum * BV.y + ps0 * W0.y + ps1 * W1.y + ps2 * W2.y);
            o.z = g4.z + fw * (wsum * BV.z + ps0 * W0.z + ps1 * W1.z + ps2 * W2.z);
            o.w = g4.w + fw * (wsum * BV.w + ps0 * W0.w + ps1 * W1.w + ps2 * W2.w);
            out4[item] = o;
        }
        __syncthreads();   // protect sMeta if this block takes another unit
    }
}

extern "C" void kernel_launch(void* const* d_in, const int* in_sizes, int n_in,
                              void* d_out, int out_size, void* d_ws, size_t ws_size,
                              hipStream_t stream) {
    const float* images    = (const float*)d_in[0];
    const float* positions = (const float*)d_in[1];
    const float* gf        = (const float*)d_in[2];
    const float* Wp        = (const float*)d_in[3];
    const float* bp        = (const float*)d_in[4];
    const float* w1        = (const float*)d_in[5];
    const float* b1        = (const float*)d_in[6];
    const float* w2        = (const float*)d_in[7];
    const float* b2        = (const float*)d_in[8];

    int B = in_sizes[1] / 2;   // positions is (B,2)

    float* ws     = (float*)d_ws;
    float* pooled = ws;                          // B*3*196
    float* Af     = ws + (size_t)B * 3 * L;      // 288
    float* B0f    = Af + 3 * HID;                // 96

    // co-residency: query actual max blocks/CU for this kernel, cap grid there
    int perCU = 0;
    hipOccupancyMaxActiveBlocksPerMultiprocessor(&perCU, (const void*)mega_kernel, 256, 0);
    if (perCU < 1) perCU = 1;
    int grid = perCU * 256;          // 256 CUs on MI355X
    if (grid > 2048) grid = 2048;

    float* outp = (float*)d_out;
    void* args[] = { (void*)&images, (void*)&positions, (void*)&gf, (void*)&Wp,
                     (void*)&bp, (void*)&w1, (void*)&b1, (void*)&w2, (void*)&b2,
                     (void*)&outp, (void*)&pooled, (void*)&Af, (void*)&B0f,
                     (void*)&B };
    hipLaunchCooperativeKernel((const void*)mega_kernel, dim3(grid), dim3(256),
                               args, 0, stream);
}

// Round 7
// 103.440 us; speedup vs baseline: 2.0944x; 2.0944x over previous
//
#include <hip/hip_runtime.h>
#include <math.h>

#define H_IMG 256
#define W_IMG 512
#define FS    14
#define L     196
#define DM    384
#define HID   96
#define TPB   32    // tokens per block in fused update kernel
#define NREP  4     // measurement: run each kernel body 4x

// ---- replicate reference x_start / y_start computation ----
__device__ __forceinline__ void get_starts(const float* __restrict__ pos, int b,
                                           int& xs, int& ys) {
    float px = fminf(fmaxf(pos[b * 2 + 0], 0.f), 1.f);
    float py = fminf(fmaxf(pos[b * 2 + 1], 0.f), 1.f);
    int xv = (int)truncf(px * (float)W_IMG - 112.f);
    xs = ((xv % W_IMG) + W_IMG) % W_IMG;
    float yv = fminf(fmaxf(py * (float)H_IMG - 112.f, 0.f), (float)(H_IMG - 224));
    ys = (int)floorf(yv);
}

// ---- K1: r2-exact pool body, repeated NREP times (disjoint outputs) ----
// grid = B*14 blocks, 256 threads (224 active). Scalar loads are wave-coalesced.
__global__ __launch_bounds__(256) void pool_x4_kernel(
    const float* __restrict__ img, const float* __restrict__ pos,
    const float* __restrict__ Wp,  const float* __restrict__ bp,
    const float* __restrict__ w1,  const float* __restrict__ b1,
    float* __restrict__ pooled,    // NREP consecutive regions of B*3*L
    float* __restrict__ A, float* __restrict__ B0,
    int B)
{
    const int HW = H_IMG * W_IMG;
    const size_t PSTRIDE = (size_t)B * 3 * L;
    int blk = blockIdx.x;
    int b = blk / FS;
    int i = blk % FS;
    int t = threadIdx.x;
    int xs, ys;
    get_starts(pos, b, xs, ys);

    #pragma unroll 1
    for (int rep = 0; rep < NREP; ++rep) {
        if (t < 224) {
            int col = xs + t;
            if (col >= W_IMG) col -= W_IMG;   // wraparound
            int row0 = ys + i * 16;
            const float* ip = img + (size_t)b * 3 * HW + (size_t)row0 * W_IMG + col;
            float a0 = 0.f, a1 = 0.f, a2 = 0.f;
            #pragma unroll
            for (int dy = 0; dy < 16; ++dy) {
                const float* r = ip + dy * W_IMG;
                a0 += r[0];
                a1 += r[HW];
                a2 += r[2 * HW];
            }
            #pragma unroll
            for (int d = 1; d < 16; d <<= 1) {
                a0 += __shfl_xor(a0, d);
                a1 += __shfl_xor(a1, d);
                a2 += __shfl_xor(a2, d);
            }
            if ((t & 15) == 0) {
                int li = i * FS + (t >> 4);
                float* pr = pooled + rep * PSTRIDE;
                pr[((size_t)b * 3 + 0) * L + li] = a0 * (1.f / 256.f);
                pr[((size_t)b * 3 + 1) * L + li] = a1 * (1.f / 256.f);
                pr[((size_t)b * 3 + 2) * L + li] = a2 * (1.f / 256.f);
            }
        }
    }

    // ---- side job on block 0: fold A = Wp@w1, B0 = bp@w1 + b1 (once) ----
    if (blk == 0 && t < HID) {
        float a0 = 0.f, a1 = 0.f, a2 = 0.f, ab = 0.f;
        #pragma unroll 4
        for (int d = 0; d < DM; ++d) {
            float wv = w1[d * HID + t];
            a0 += Wp[d] * wv;
            a1 += Wp[DM + d] * wv;
            a2 += Wp[2 * DM + d] * wv;
            ab += bp[d] * wv;
        }
        A[t] = a0; A[HID + t] = a1; A[2 * HID + t] = a2;
        B0[t] = ab + b1[t];
    }
}

// ---- K2: r2-exact fused update body, repeated NREP times ----
// rep 0 writes d_out; reps 1..3 write a ws scratch region (same values).
__global__ __launch_bounds__(256) void update_x4_kernel(
    const float* __restrict__ pos, const float* __restrict__ pooled,
    const float* __restrict__ A,   const float* __restrict__ B0,
    const float* __restrict__ w2,  const float* __restrict__ b2,
    const float* __restrict__ gf,  const float* __restrict__ Wp,
    const float* __restrict__ bp,  float* __restrict__ out,
    float* __restrict__ scratch, int B)
{
    __shared__ float  sA[3 * HID];
    __shared__ float  sB0[HID];
    __shared__ float  sw2[HID];
    __shared__ float4 sWp4[3 * DM / 4];
    __shared__ float4 sbp4[DM / 4];
    __shared__ float  sMeta[TPB][5];

    int tid = threadIdx.x;
    if (tid < 3 * HID) sA[tid] = A[tid];
    if (tid < HID) { sB0[tid] = B0[tid]; sw2[tid] = w2[tid]; }
    if (tid < 288) sWp4[tid] = ((const float4*)Wp)[tid];
    if (tid < 96)  sbp4[tid] = ((const float4*)bp)[tid];
    __syncthreads();

    const int nTok = B * L;
    int bt = blockIdx.x * TPB;
    int g = tid >> 3;
    int s = tid & 7;
    int token = bt + g;
    if (token >= nTok) token = nTok - 1;
    int b = token / L;
    int l = token % L;

    #pragma unroll 1
    for (int rep = 0; rep < NREP; ++rep) {
        const float* pb = pooled + (size_t)b * 3 * L;
        float p0 = pb[l], p1 = pb[L + l], p2 = pb[2 * L + l];

        float acc = 0.0f;
        #pragma unroll
        for (int m = 0; m < 12; ++m) {
            int k = s + 8 * m;
            float x = sB0[k] + p0 * sA[k] + p1 * sA[HID + k] + p2 * sA[2 * HID + k];
            float e = __expf(1.5957691216057308f * (x + 0.044715f * x * x * x));
            float th = 1.0f - 2.0f / (e + 1.0f);
            acc += 0.5f * x * (1.0f + th) * sw2[k];
        }
        acc += __shfl_xor(acc, 1);
        acc += __shfl_xor(acc, 2);
        acc += __shfl_xor(acc, 4);

        if (s == 0) {
            float fw = 1.0f / (1.0f + __expf(-(acc + b2[0])));

            int xs, ys;
            get_starts(pos, b, xs, ys);
            int i = l / FS, j = l % FS;
            float uj = ((j + 0.5f) * 2.0f) / 14.0f - 1.0f;
            float ui = ((i + 0.5f) * 2.0f) / 14.0f - 1.0f;
            float gx = (224.0f / 512.0f) * uj + ((2.0f * (float)xs + 224.0f) / 512.0f - 1.0f);
            float gy = (224.0f / 256.0f) * ui + ((2.0f * (float)ys + 224.0f) / 256.0f - 1.0f);
            float ix = (gx + 1.0f) * 7.0f - 0.5f;
            float iy = (gy + 1.0f) * 7.0f - 0.5f;
            float x0f = floorf(ix), y0f = floorf(iy);
            float wx1 = ix - x0f, wx0 = 1.0f - wx1;
            float wy1 = iy - y0f, wy0 = 1.0f - wy1;
            int x0 = (int)x0f, y0 = (int)y0f;
            int x1 = x0 + 1, y1 = y0 + 1;

            float ps0 = 0.f, ps1 = 0.f, ps2 = 0.f, wsum = 0.f;
            const int   cx[4] = { x0, x1, x0, x1 };
            const int   cy[4] = { y0, y0, y1, y1 };
            const float cw[4] = { wy0 * wx0, wy0 * wx1, wy1 * wx0, wy1 * wx1 };
            #pragma unroll
            for (int n = 0; n < 4; ++n) {
                int X = cx[n], Y = cy[n];
                if (X >= 0 && X < FS && Y >= 0 && Y < FS) {
                    float w = cw[n];
                    int li = Y * FS + X;
                    ps0 += w * pb[li];
                    ps1 += w * pb[L + li];
                    ps2 += w * pb[2 * L + li];
                    wsum += w;
                }
            }
            sMeta[g][0] = fw;  sMeta[g][1] = wsum;
            sMeta[g][2] = ps0; sMeta[g][3] = ps1; sMeta[g][4] = ps2;
        }
        __syncthreads();

        float* dst = (rep == 0) ? out : scratch;
        const float4* gf4  = (const float4*)gf  + (size_t)bt * (DM / 4);
        float4*       out4 = (float4*)dst       + (size_t)bt * (DM / 4);
        long long maxItem = (long long)(nTok - bt) * (DM / 4);
        #pragma unroll
        for (int it = 0; it < 12; ++it) {
            int item = it * 256 + tid;
            if (item >= maxItem) break;
            int tl = item / (DM / 4);
            int d4 = item - tl * (DM / 4);
            float fw   = sMeta[tl][0];
            float wsum = sMeta[tl][1];
            float ps0  = sMeta[tl][2];
            float ps1  = sMeta[tl][3];
            float ps2  = sMeta[tl][4];
            float4 g4 = gf4[item];
            float4 W0 = sWp4[d4];
            float4 W1 = sWp4[96 + d4];
            float4 W2 = sWp4[192 + d4];
            float4 BV = sbp4[d4];
            float4 o;
            o.x = g4.x + fw * (wsum * BV.x + ps0 * W0.x + ps1 * W1.x + ps2 * W2.x);
            o.y = g4.y + fw * (wsum * BV.y + ps0 * W0.y + ps1 * W1.y + ps2 * W2.y);
            o.z = g4.z + fw * (wsum * BV.z + ps0 * W0.z + ps1 * W1.z + ps2 * W2.z);
            o.w = g4.w + fw * (wsum * BV.w + ps0 * W0.w + ps1 * W1.w + ps2 * W2.w);
            out4[item] = o;
        }
        __syncthreads();   // protect sMeta across reps
    }
}

extern "C" void kernel_launch(void* const* d_in, const int* in_sizes, int n_in,
                              void* d_out, int out_size, void* d_ws, size_t ws_size,
                              hipStream_t stream) {
    const float* images    = (const float*)d_in[0];
    const float* positions = (const float*)d_in[1];
    const float* gf        = (const float*)d_in[2];
    const float* Wp        = (const float*)d_in[3];
    const float* bp        = (const float*)d_in[4];
    const float* w1        = (const float*)d_in[5];
    const float* b1        = (const float*)d_in[6];
    const float* w2        = (const float*)d_in[7];
    const float* b2        = (const float*)d_in[8];

    const int B = in_sizes[1] / 2;   // positions is (B,2)
    const int nTok = B * L;

    float* ws      = (float*)d_ws;
    float* pooled  = ws;                               // NREP * B*3*196
    float* A       = ws + (size_t)NREP * B * 3 * L;    // 288
    float* B0      = A + 3 * HID;                      // 96
    float* scratch = B0 + HID;                         // nTok*DM (update dup)

    hipLaunchKernelGGL(pool_x4_kernel, dim3(B * FS), dim3(256), 0, stream,
                       images, positions, Wp, bp, w1, b1, pooled, A, B0, B);

    hipLaunchKernelGGL(update_x4_kernel, dim3((nTok + TPB - 1) / TPB), dim3(256), 0, stream,
                       positions, pooled, A, B0, w2, b2, gf, Wp, bp,
                       (float*)d_out, scratch, B);
}

// Round 8
// 62.709 us; speedup vs baseline: 3.4547x; 1.6495x over previous
//
#include <hip/hip_runtime.h>
#include <math.h>

#define H_IMG 256
#define W_IMG 512
#define FS    14
#define L     196
#define DM    384
#define HID   96
#define TPB   32    // tokens per block in fused update kernel

// ---- replicate reference x_start / y_start computation ----
__device__ __forceinline__ void get_starts(const float* __restrict__ pos, int b,
                                           int& xs, int& ys) {
    float px = fminf(fmaxf(pos[b * 2 + 0], 0.f), 1.f);
    float py = fminf(fmaxf(pos[b * 2 + 1], 0.f), 1.f);
    int xv = (int)truncf(px * (float)W_IMG - 112.f);
    xs = ((xv % W_IMG) + W_IMG) % W_IMG;
    float yv = fminf(fmaxf(py * (float)H_IMG - 112.f, 0.f), (float)(H_IMG - 224));
    ys = (int)floorf(yv);
}

// ---- K1: r2-exact pool body. Every 4th block instead prefetches a slice of
// gf into L3 (pure float4 load stream + wave-reduce sink) so that (a) HBM is
// saturated during pool's latency gaps and (b) update's gf read is L3-warm. ----
__global__ __launch_bounds__(256) void pool_pre_kernel(
    const float* __restrict__ img, const float* __restrict__ pos,
    const float* __restrict__ Wp,  const float* __restrict__ bp,
    const float* __restrict__ w1,  const float* __restrict__ b1,
    const float* __restrict__ gf,
    float* __restrict__ pooled, float* __restrict__ A, float* __restrict__ B0,
    float* __restrict__ pfsink, int B, int nPF)
{
    const int HW = H_IMG * W_IMG;
    const int idx = blockIdx.x;
    const int t = threadIdx.x;

    if ((idx & 3) == 3) {
        // ---- prefetch role: stream gf slice, reduce, sink ----
        int pfb = idx >> 2;                       // 0 .. nPF-1
        const int ngf4 = B * L * (DM / 4);        // gf as float4 count
        const float4* g4 = (const float4*)gf;
        float acc = 0.f;
        for (int j = pfb * 256 + t; j < ngf4; j += nPF * 256) {
            float4 v = g4[j];
            acc += v.x + v.y + v.z + v.w;
        }
        #pragma unroll
        for (int d = 1; d < 64; d <<= 1) acc += __shfl_xor(acc, d);
        if ((t & 63) == 0) pfsink[pfb * 4 + (t >> 6)] = acc;
        return;
    }

    const int poolIdx = idx - ((idx + 1) >> 2);   // compact non-PF blocks
    if (poolIdx >= B * FS) return;
    const int b = poolIdx / FS;
    const int i = poolIdx % FS;
    int xs, ys;
    get_starts(pos, b, xs, ys);

    if (t < 224) {
        int col = xs + t;
        if (col >= W_IMG) col -= W_IMG;   // wraparound
        int row0 = ys + i * 16;
        const float* ip = img + (size_t)b * 3 * HW + (size_t)row0 * W_IMG + col;
        float a0 = 0.f, a1 = 0.f, a2 = 0.f;
        #pragma unroll
        for (int dy = 0; dy < 16; ++dy) {
            const float* r = ip + dy * W_IMG;
            a0 += r[0];
            a1 += r[HW];
            a2 += r[2 * HW];
        }
        #pragma unroll
        for (int d = 1; d < 16; d <<= 1) {
            a0 += __shfl_xor(a0, d);
            a1 += __shfl_xor(a1, d);
            a2 += __shfl_xor(a2, d);
        }
        if ((t & 15) == 0) {
            int li = i * FS + (t >> 4);
            pooled[((size_t)b * 3 + 0) * L + li] = a0 * (1.f / 256.f);
            pooled[((size_t)b * 3 + 1) * L + li] = a1 * (1.f / 256.f);
            pooled[((size_t)b * 3 + 2) * L + li] = a2 * (1.f / 256.f);
        }
    }

    // ---- side job on pool block 0: fold A = Wp@w1, B0 = bp@w1 + b1 ----
    if (poolIdx == 0 && t < HID) {
        float a0 = 0.f, a1 = 0.f, a2 = 0.f, ab = 0.f;
        #pragma unroll 4
        for (int d = 0; d < DM; ++d) {
            float wv = w1[d * HID + t];
            a0 += Wp[d] * wv;
            a1 += Wp[DM + d] * wv;
            a2 += Wp[2 * DM + d] * wv;
            ab += bp[d] * wv;
        }
        A[t] = a0; A[HID + t] = a1; A[2 * HID + t] = a2;
        B0[t] = ab + b1[t];
    }
}

// ---- K2 (unchanged r2 champion): fw + bilinear + gated update ----
__global__ __launch_bounds__(256) void fused_update_kernel(
    const float* __restrict__ pos, const float* __restrict__ pooled,
    const float* __restrict__ A,   const float* __restrict__ B0,
    const float* __restrict__ w2,  const float* __restrict__ b2,
    const float* __restrict__ gf,  const float* __restrict__ Wp,
    const float* __restrict__ bp,  float* __restrict__ out, int B)
{
    __shared__ float  sA[3 * HID];
    __shared__ float  sB0[HID];
    __shared__ float  sw2[HID];
    __shared__ float4 sWp4[3 * DM / 4];
    __shared__ float4 sbp4[DM / 4];
    __shared__ float  sMeta[TPB][5];

    int tid = threadIdx.x;
    if (tid < 3 * HID) sA[tid] = A[tid];
    if (tid < HID) { sB0[tid] = B0[tid]; sw2[tid] = w2[tid]; }
    if (tid < 288) sWp4[tid] = ((const float4*)Wp)[tid];
    if (tid < 96)  sbp4[tid] = ((const float4*)bp)[tid];
    __syncthreads();

    const int nTok = B * L;
    int bt = blockIdx.x * TPB;
    int g = tid >> 3;
    int s = tid & 7;
    int token = bt + g;
    if (token >= nTok) token = nTok - 1;
    int b = token / L;
    int l = token % L;

    const float* pb = pooled + (size_t)b * 3 * L;
    float p0 = pb[l], p1 = pb[L + l], p2 = pb[2 * L + l];

    float acc = 0.0f;
    #pragma unroll
    for (int m = 0; m < 12; ++m) {
        int k = s + 8 * m;
        float x = sB0[k] + p0 * sA[k] + p1 * sA[HID + k] + p2 * sA[2 * HID + k];
        float e = __expf(1.5957691216057308f * (x + 0.044715f * x * x * x));
        float th = 1.0f - 2.0f / (e + 1.0f);
        acc += 0.5f * x * (1.0f + th) * sw2[k];
    }
    acc += __shfl_xor(acc, 1);
    acc += __shfl_xor(acc, 2);
    acc += __shfl_xor(acc, 4);

    if (s == 0) {
        float fw = 1.0f / (1.0f + __expf(-(acc + b2[0])));

        int xs, ys;
        get_starts(pos, b, xs, ys);
        int i = l / FS, j = l % FS;
        float uj = ((j + 0.5f) * 2.0f) / 14.0f - 1.0f;
        float ui = ((i + 0.5f) * 2.0f) / 14.0f - 1.0f;
        float gx = (224.0f / 512.0f) * uj + ((2.0f * (float)xs + 224.0f) / 512.0f - 1.0f);
        float gy = (224.0f / 256.0f) * ui + ((2.0f * (float)ys + 224.0f) / 256.0f - 1.0f);
        float ix = (gx + 1.0f) * 7.0f - 0.5f;
        float iy = (gy + 1.0f) * 7.0f - 0.5f;
        float x0f = floorf(ix), y0f = floorf(iy);
        float wx1 = ix - x0f, wx0 = 1.0f - wx1;
        float wy1 = iy - y0f, wy0 = 1.0f - wy1;
        int x0 = (int)x0f, y0 = (int)y0f;
        int x1 = x0 + 1, y1 = y0 + 1;

        float ps0 = 0.f, ps1 = 0.f, ps2 = 0.f, wsum = 0.f;
        const int   cx[4] = { x0, x1, x0, x1 };
        const int   cy[4] = { y0, y0, y1, y1 };
        const float cw[4] = { wy0 * wx0, wy0 * wx1, wy1 * wx0, wy1 * wx1 };
        #pragma unroll
        for (int n = 0; n < 4; ++n) {
            int X = cx[n], Y = cy[n];
            if (X >= 0 && X < FS && Y >= 0 && Y < FS) {
                float w = cw[n];
                int li = Y * FS + X;
                ps0 += w * pb[li];
                ps1 += w * pb[L + li];
                ps2 += w * pb[2 * L + li];
                wsum += w;
            }
        }
        sMeta[g][0] = fw;  sMeta[g][1] = wsum;
        sMeta[g][2] = ps0; sMeta[g][3] = ps1; sMeta[g][4] = ps2;
    }
    __syncthreads();

    const float4* gf4  = (const float4*)gf  + (size_t)bt * (DM / 4);
    float4*       out4 = (float4*)out       + (size_t)bt * (DM / 4);
    long long maxItem = (long long)(nTok - bt) * (DM / 4);
    #pragma unroll
    for (int it = 0; it < 12; ++it) {
        int item = it * 256 + tid;
        if (item >= maxItem) break;
        int tl = item / (DM / 4);
        int d4 = item - tl * (DM / 4);
        float fw   = sMeta[tl][0];
        float wsum = sMeta[tl][1];
        float ps0  = sMeta[tl][2];
        float ps1  = sMeta[tl][3];
        float ps2  = sMeta[tl][4];
        float4 g4 = gf4[item];
        float4 W0 = sWp4[d4];
        float4 W1 = sWp4[96 + d4];
        float4 W2 = sWp4[192 + d4];
        float4 BV = sbp4[d4];
        float4 o;
        o.x = g4.x + fw * (wsum * BV.x + ps0 * W0.x + ps1 * W1.x + ps2 * W2.x);
        o.y = g4.y + fw * (wsum * BV.y + ps0 * W0.y + ps1 * W1.y + ps2 * W2.y);
        o.z = g4.z + fw * (wsum * BV.z + ps0 * W0.z + ps1 * W1.z + ps2 * W2.z);
        o.w = g4.w + fw * (wsum * BV.w + ps0 * W0.w + ps1 * W1.w + ps2 * W2.w);
        out4[item] = o;
    }
}

extern "C" void kernel_launch(void* const* d_in, const int* in_sizes, int n_in,
                              void* d_out, int out_size, void* d_ws, size_t ws_size,
                              hipStream_t stream) {
    const float* images    = (const float*)d_in[0];
    const float* positions = (const float*)d_in[1];
    const float* gf        = (const float*)d_in[2];
    const float* Wp        = (const float*)d_in[3];
    const float* bp        = (const float*)d_in[4];
    const float* w1        = (const float*)d_in[5];
    const float* b1        = (const float*)d_in[6];
    const float* w2        = (const float*)d_in[7];
    const float* b2        = (const float*)d_in[8];

    const int B = in_sizes[1] / 2;   // positions is (B,2)
    const int nTok = B * L;
    const int nPool = B * FS;

    float* ws     = (float*)d_ws;
    float* pooled = ws;                          // B*3*196
    float* A      = ws + (size_t)B * 3 * L;      // 288
    float* B0     = A + 3 * HID;                 // 96
    float* pfsink = B0 + HID;                    // nPF*4 sink floats

    // every 4th block is a gf-prefetch block; pool slots = 3/4 of grid
    int grid1 = 4 * ((nPool + 2) / 3);
    int nPF   = grid1 >> 2;

    hipLaunchKernelGGL(pool_pre_kernel, dim3(grid1), dim3(256), 0, stream,
                       images, positions, Wp, bp, w1, b1, gf,
                       pooled, A, B0, pfsink, B, nPF);

    hipLaunchKernelGGL(fused_update_kernel, dim3((nTok + TPB - 1) / TPB), dim3(256), 0, stream,
                       positions, pooled, A, B0, w2, b2, gf, Wp, bp, (float*)d_out, B);
}